// Round 1
// baseline (292.317 us; speedup 1.0000x reference)
//
#include <hip/hip_runtime.h>

#define NN 50000
#define EE 600000
#define INF 256
#define HF 128
#define CEB ((EE + 255) / 256)   // 2344 blocks for edge-parallel work

typedef __attribute__((ext_vector_type(8))) short short8;
typedef __attribute__((ext_vector_type(4))) float floatx4;

// ---------------- bf16 helpers ----------------
__device__ __forceinline__ unsigned short f32_to_bf16_rne(float x) {
    unsigned int u = __float_as_uint(x);
    unsigned int r = (u + 0x7FFFu + ((u >> 16) & 1u)) >> 16;
    return (unsigned short)r;
}
__device__ __forceinline__ float bf16_to_f32(unsigned short h) {
    return __uint_as_float(((unsigned int)h) << 16);
}
__device__ __forceinline__ float bf16lo_u32(unsigned int u) {
    return __uint_as_float(u << 16);
}
__device__ __forceinline__ float bf16hi_u32(unsigned int u) {
    return __uint_as_float(u & 0xFFFF0000u);
}
// 8 f32 -> hi/lo bf16 fragment pair
__device__ __forceinline__ void cvt_hilo8(float4 v0, float4 v1, short8& hs, short8& ls) {
    float x[8] = {v0.x, v0.y, v0.z, v0.w, v1.x, v1.y, v1.z, v1.w};
    union { short8 s; unsigned short u[8]; } H, L;
#pragma unroll
    for (int k = 0; k < 8; ++k) {
        unsigned short hi = f32_to_bf16_rne(x[k]);
        H.u[k] = hi;
        L.u[k] = f32_to_bf16_rne(x[k] - bf16_to_f32(hi));
    }
    hs = H.s;
    ls = L.s;
}

// ---------------- fused: degree counting (saving per-edge rank) + weight prepack -------
__global__ void count_and_prepack(const int* __restrict__ row, int* __restrict__ cnt,
                                  int* __restrict__ pos, int E,
                                  const float* __restrict__ lw, const float* __restrict__ cw,
                                  unsigned short* __restrict__ fl, unsigned short* __restrict__ fc) {
    int b = blockIdx.x;
    if (b < CEB) {
        int e = b * 256 + threadIdx.x;
        if (e < E) pos[e] = atomicAdd(&cnt[row[e]], 1);
        return;
    }
    int idx = (b - CEB) * 256 + threadIdx.x;
    const float* src;
    unsigned short* dst;
    int K, c;
    if (idx < 8192) {
        src = lw; dst = fl; K = INF; c = idx;
    } else if (idx < 12288) {
        src = cw; dst = fc; K = HF; c = idx - 8192;
    } else return;
    int lane = c & 63;
    int nt = (c >> 6) & 7;
    int hl = (c >> 9) & 1;
    int kc = c >> 10;
    int rw = nt * 16 + (lane & 15);
    int koff = kc * 32 + (lane >> 4) * 8;
    const float* p = &src[(size_t)rw * K + koff];
    float4 v0 = *reinterpret_cast<const float4*>(p);
    float4 v1 = *reinterpret_cast<const float4*>(p + 4);
    short8 hs, ls;
    cvt_hilo8(v0, v1, hs, ls);
    *reinterpret_cast<short8*>(&dst[(size_t)c * 8]) = hl ? ls : hs;
}

// ---------------- scan phase1: per-block sums of cnt ----------------
__global__ void scan_phase1(const int* __restrict__ cnt, int* __restrict__ bsum, int n) {
    __shared__ int sdata[256];
    int t = threadIdx.x;
    int i = blockIdx.x * 256 + t;
    sdata[t] = (i < n) ? cnt[i] : 0;
    __syncthreads();
    for (int s = 128; s > 0; s >>= 1) {
        if (t < s) sdata[t] += sdata[t + s];
        __syncthreads();
    }
    if (t == 0) bsum[blockIdx.x] = sdata[0];
}

// ---------------- scan phase2+3 fused (+ finalize_deg) ----------------
__global__ void scan_phase3(const int* __restrict__ cnt, const int* __restrict__ bsum,
                            int* __restrict__ row_start,
                            float* __restrict__ deg_inv, float* __restrict__ dis,
                            int n, int nb, int E) {
    __shared__ int sb[256];
    __shared__ int sdata[256];
    int t = threadIdx.x;
    sb[t] = (t < nb) ? bsum[t] : 0;
    __syncthreads();
    for (int s = 1; s < 256; s <<= 1) {
        int add = (t >= s) ? sb[t - s] : 0;
        __syncthreads();
        sb[t] += add;
        __syncthreads();
    }
    int base = sb[blockIdx.x] - bsum[blockIdx.x];
    int i = blockIdx.x * 256 + t;
    int v = (i < n) ? cnt[i] : 0;
    sdata[t] = v;
    __syncthreads();
    for (int s = 1; s < 256; s <<= 1) {
        int add = (t >= s) ? sdata[t - s] : 0;
        __syncthreads();
        sdata[t] += add;
        __syncthreads();
    }
    if (i < n) {
        int ex = base + sdata[t] - v;
        row_start[i] = ex;
        float d = (float)(v + 1);
        deg_inv[i] = 1.0f / d;
        dis[i] = rsqrtf(d);
    }
    if (blockIdx.x == 0 && t == 0) row_start[n] = E;
}

// ---------------- fused GEMM:
//   MODE 0: fill_csr tail blocks + (in_feat @ lin_w.T + b) with bf16 split MFMA
//   MODE 1/2: per-lane register aggregation (replaces separate aggregate kernel)
//             directly producing MFMA A-fragments, then conv GEMM + epilogue.
template <int K, int MODE>
__global__ __launch_bounds__(256) void gemm_fused(
    const float* __restrict__ Af,
    const unsigned short* __restrict__ hbf_in,
    const unsigned short* __restrict__ Wf,
    const float* __restrict__ bias,
    float* __restrict__ C, unsigned short* __restrict__ Cbf,
    const float* __restrict__ h, const float* __restrict__ deg_inv,
    const float* __restrict__ dis, const float* __restrict__ root,
    const float* __restrict__ gamma, const float* __restrict__ beta,
    const int* __restrict__ row_start, int* __restrict__ csr_col,
    const int* __restrict__ row, const int* __restrict__ col,
    const int* __restrict__ pos, int fill_blocks, int M) {
    constexpr int NKC = K / 32;
    __shared__ unsigned short WS[2 * 8192];   // 2 kc x 16KB = 32KB

    int bidx = blockIdx.x;
    if (MODE == 0) {
        // leading blocks: atomic-free CSR fill, overlapped with the big GEMM
        if (bidx < fill_blocks) {
            int e = bidx * 256 + threadIdx.x;
            if (e < EE) {
                int pp = row_start[row[e]] + pos[e];
                __builtin_nontemporal_store(col[e], &csr_col[pp]);
            }
            return;
        }
        bidx -= fill_blocks;
    }

    const int t = threadIdx.x;
    const int wave = t >> 6;
    const int lane = t & 63;
    const int lrow = lane & 15;
    const int quad = lane >> 4;
    const int bm = bidx * 64;
    int arow = bm + wave * 16 + lrow;
    if (arow >= M) arow = M - 1;   // clamp; stores are predicated

    // -------- per-lane neighbor aggregation straight into A-fragments --------
    // lane (wave,lrow,quad) owns node arow, features kc*32+quad*8 .. +8 (kc=0..3)
    short8 ah[NKC], al[NKC];
    if (MODE >= 1) {
        const int node = arow;
        int s = row_start[node];
        int e = row_start[node + 1];
        float a[NKC][8];
#pragma unroll
        for (int kc = 0; kc < NKC; ++kc)
#pragma unroll
            for (int k = 0; k < 8; ++k) a[kc][k] = 0.f;
        int j = s;
        for (; j + 1 < e; j += 2) {
            int c0 = csr_col[j];
            int c1 = csr_col[j + 1];
            const unsigned short* p0 = &hbf_in[(size_t)c0 * HF + quad * 8];
            const unsigned short* p1 = &hbf_in[(size_t)c1 * HF + quad * 8];
            uint4 g0[NKC], g1[NKC];
#pragma unroll
            for (int kc = 0; kc < NKC; ++kc) {
                g0[kc] = *reinterpret_cast<const uint4*>(p0 + kc * 32);
                g1[kc] = *reinterpret_cast<const uint4*>(p1 + kc * 32);
            }
#pragma unroll
            for (int kc = 0; kc < NKC; ++kc) {
                a[kc][0] += bf16lo_u32(g0[kc].x) + bf16lo_u32(g1[kc].x);
                a[kc][1] += bf16hi_u32(g0[kc].x) + bf16hi_u32(g1[kc].x);
                a[kc][2] += bf16lo_u32(g0[kc].y) + bf16lo_u32(g1[kc].y);
                a[kc][3] += bf16hi_u32(g0[kc].y) + bf16hi_u32(g1[kc].y);
                a[kc][4] += bf16lo_u32(g0[kc].z) + bf16lo_u32(g1[kc].z);
                a[kc][5] += bf16hi_u32(g0[kc].z) + bf16hi_u32(g1[kc].z);
                a[kc][6] += bf16lo_u32(g0[kc].w) + bf16lo_u32(g1[kc].w);
                a[kc][7] += bf16hi_u32(g0[kc].w) + bf16hi_u32(g1[kc].w);
            }
        }
        if (j < e) {
            int c0 = csr_col[j];
            const unsigned short* p0 = &hbf_in[(size_t)c0 * HF + quad * 8];
#pragma unroll
            for (int kc = 0; kc < NKC; ++kc) {
                uint4 g = *reinterpret_cast<const uint4*>(p0 + kc * 32);
                a[kc][0] += bf16lo_u32(g.x);
                a[kc][1] += bf16hi_u32(g.x);
                a[kc][2] += bf16lo_u32(g.y);
                a[kc][3] += bf16hi_u32(g.y);
                a[kc][4] += bf16lo_u32(g.z);
                a[kc][5] += bf16hi_u32(g.z);
                a[kc][6] += bf16lo_u32(g.w);
                a[kc][7] += bf16hi_u32(g.w);
            }
        }
        // agg = dis[node]*sum + deg_inv[node]*h[node]  (self-loop term), then hi/lo split
        float dn = dis[node];
        float di = deg_inv[node];
#pragma unroll
        for (int kc = 0; kc < NKC; ++kc) {
            const float* hp = &h[(size_t)node * HF + kc * 32 + quad * 8];
            float4 hv0 = *reinterpret_cast<const float4*>(hp);
            float4 hv1 = *reinterpret_cast<const float4*>(hp + 4);
            float4 o0, o1;
            o0.x = fmaf(dn, a[kc][0], di * hv0.x);
            o0.y = fmaf(dn, a[kc][1], di * hv0.y);
            o0.z = fmaf(dn, a[kc][2], di * hv0.z);
            o0.w = fmaf(dn, a[kc][3], di * hv0.w);
            o1.x = fmaf(dn, a[kc][4], di * hv1.x);
            o1.y = fmaf(dn, a[kc][5], di * hv1.y);
            o1.z = fmaf(dn, a[kc][6], di * hv1.z);
            o1.w = fmaf(dn, a[kc][7], di * hv1.w);
            cvt_hilo8(o0, o1, ah[kc], al[kc]);
        }
    }

    floatx4 acc[8];
#pragma unroll
    for (int nt = 0; nt < 8; ++nt) acc[nt] = (floatx4){0.f, 0.f, 0.f, 0.f};

#pragma unroll
    for (int p = 0; p < NKC / 2; ++p) {
        if (p) __syncthreads();
        {
            const uint4* src = reinterpret_cast<const uint4*>(Wf + (size_t)p * 16384);
            uint4* dstl = reinterpret_cast<uint4*>(WS);
#pragma unroll
            for (int i = 0; i < 8; ++i) dstl[t + 256 * i] = src[t + 256 * i];
        }
        __syncthreads();
#pragma unroll
        for (int k2 = 0; k2 < 2; ++k2) {
            int kc = p * 2 + k2;
            short8 afh, afl;
            if (MODE == 0) {
                const float* ap = &Af[(size_t)arow * K + kc * 32 + quad * 8];
                float4 a0 = *reinterpret_cast<const float4*>(ap);
                float4 a1 = *reinterpret_cast<const float4*>(ap + 4);
                cvt_hilo8(a0, a1, afh, afl);
            } else {
                afh = ah[kc];
                afl = al[kc];
            }
            const unsigned short* wb = &WS[k2 * 8192 + lane * 8];
#pragma unroll
            for (int nt = 0; nt < 8; ++nt) {
                short8 bfh = *reinterpret_cast<const short8*>(wb + nt * 512);
                short8 bfl = *reinterpret_cast<const short8*>(wb + 4096 + nt * 512);
                acc[nt] = __builtin_amdgcn_mfma_f32_16x16x32_bf16(afh, bfh, acc[nt], 0, 0, 0);
                acc[nt] = __builtin_amdgcn_mfma_f32_16x16x32_bf16(afl, bfh, acc[nt], 0, 0, 0);
                acc[nt] = __builtin_amdgcn_mfma_f32_16x16x32_bf16(afh, bfl, acc[nt], 0, 0, 0);
            }
        }
    }

    float cb[8], rt[8], gm[8], bt[8];
#pragma unroll
    for (int nt = 0; nt < 8; ++nt) {
        int colh = nt * 16 + lrow;
        cb[nt] = bias[colh];
        if (MODE >= 1) rt[nt] = root[colh];
        if (MODE == 1) { gm[nt] = gamma[colh]; bt[nt] = beta[colh]; }
    }

#pragma unroll
    for (int r = 0; r < 4; ++r) {
        int grow = bm + wave * 16 + quad * 4 + r;
        bool ok = (grow < M);
        int gr = ok ? grow : M - 1;
        float x[8];
        if (MODE == 0) {
#pragma unroll
            for (int nt = 0; nt < 8; ++nt) x[nt] = acc[nt][r] + cb[nt];
        } else {
            float di = deg_inv[gr];
            float hv[8];
#pragma unroll
            for (int nt = 0; nt < 8; ++nt) hv[nt] = h[(size_t)gr * HF + nt * 16 + lrow];
#pragma unroll
            for (int nt = 0; nt < 8; ++nt) {
                float v = acc[nt][r] + cb[nt] + fmaxf(hv[nt] + rt[nt], 0.f) * di;
                x[nt] = (MODE == 1) ? v + hv[nt] : v;
            }
        }
        if (MODE == 1) {
            float s = 0.f;
#pragma unroll
            for (int nt = 0; nt < 8; ++nt) s += x[nt];
#pragma unroll
            for (int m = 1; m < 16; m <<= 1) s += __shfl_xor(s, m, 64);
            float mu = s * (1.0f / HF);
            float var = 0.f;
#pragma unroll
            for (int nt = 0; nt < 8; ++nt) { float d = x[nt] - mu; var += d * d; }
#pragma unroll
            for (int m = 1; m < 16; m <<= 1) var += __shfl_xor(var, m, 64);
            float rs = rsqrtf(var * (1.0f / HF) + 1e-5f);
            float ds = dis[gr];
            if (ok) {
#pragma unroll
                for (int nt = 0; nt < 8; ++nt) {
                    int colh = nt * 16 + lrow;
                    float y = fmaxf((x[nt] - mu) * rs * gm[nt] + bt[nt], 0.f);
                    C[(size_t)grow * HF + colh] = y;
                    Cbf[(size_t)grow * HF + colh] = f32_to_bf16_rne(ds * y);
                }
            }
        } else if (MODE == 0) {
            if (ok) {
                float ds = dis[grow];
#pragma unroll
                for (int nt = 0; nt < 8; ++nt) {
                    int colh = nt * 16 + lrow;
                    C[(size_t)grow * HF + colh] = x[nt];
                    Cbf[(size_t)grow * HF + colh] = f32_to_bf16_rne(ds * x[nt]);
                }
            }
        } else {
            if (ok) {
#pragma unroll
                for (int nt = 0; nt < 8; ++nt)
                    C[(size_t)grow * HF + nt * 16 + lrow] = x[nt];
            }
        }
    }
}

extern "C" void kernel_launch(void* const* d_in, const int* in_sizes, int n_in,
                              void* d_out, int out_size, void* d_ws, size_t ws_size,
                              hipStream_t stream) {
    const int N = NN, E = EE;
    const float* in_feat = (const float*)d_in[0];
    const int* row = (const int*)d_in[1];
    const int* col = (const int*)d_in[2];
    const float* lin_w = (const float*)d_in[3];
    const float* lin_b = (const float*)d_in[4];
    const float* conv_w = (const float*)d_in[5];
    const float* conv_b = (const float*)d_in[6];
    const float* root_emb = (const float*)d_in[7];
    const float* ln_gamma = (const float*)d_in[8];
    const float* ln_beta = (const float*)d_in[9];
    float* out = (float*)d_out;

    // workspace layout (4B units); all segments kept 16B-aligned
    float* ws = (float*)d_ws;
    size_t o = 0;
    float* deg_inv = ws + o; o += N;
    float* dis = ws + o; o += N;
    int* cnt = (int*)(ws + o); o += N;
    int* row_start = (int*)(ws + o); o += N + 4;
    int* pos = (int*)(ws + o); o += E;
    int* bsum = (int*)(ws + o); o += 256;
    int* csr_col = (int*)(ws + o); o += E;
    o = (o + 3) & ~(size_t)3;
    unsigned short* fl = (unsigned short*)(ws + o); o += 32768;  // 65536 ushort (128KB)
    unsigned short* fc = (unsigned short*)(ws + o); o += 16384;  // 32768 ushort (64KB)
    float* h0 = ws + o; o += (size_t)N * HF;
    unsigned short* hbf = (unsigned short*)(ws + o); o += (size_t)N * HF / 2;
    unsigned short* hbf2 = (unsigned short*)(ws + o); o += (size_t)N * HF / 2;  // step-1 out (dbuf vs hbf)

    const int NB = (N + 255) / 256;   // 196
    const int GB = (N + 63) / 64;     // 782

    hipMemsetAsync(cnt, 0, N * sizeof(int), stream);
    count_and_prepack<<<CEB + 48, 256, 0, stream>>>(row, cnt, pos, E, lin_w, conv_w, fl, fc);
    scan_phase1<<<NB, 256, 0, stream>>>(cnt, bsum, N);
    scan_phase3<<<NB, 256, 0, stream>>>(cnt, bsum, row_start, deg_inv, dis, N, NB, E);

    // h0 = in_feat @ lin_w.T + lin_b  (f32 + dis-scaled bf16 copy); CSR fill fused as
    // leading blocks of the same launch (both depend only on count+scan).
    gemm_fused<INF, 0><<<CEB + GB, 256, 0, stream>>>(
        in_feat, nullptr, fl, lin_b, h0, hbf,
        nullptr, nullptr, dis, nullptr, nullptr, nullptr,
        row_start, csr_col, row, col, pos, CEB, N);

    // ---- prop step 0: in-register aggregate + conv + residual/LN/ReLU epilogue ----
    // reads hbf (neighbors), writes hbf2 (double buffer: cross-block read/write hazard)
    gemm_fused<HF, 1><<<GB, 256, 0, stream>>>(
        nullptr, hbf, fc, conv_b, h0, hbf2,
        h0, deg_inv, dis, root_emb, ln_gamma + HF, ln_beta + HF,
        row_start, csr_col, nullptr, nullptr, nullptr, 0, N);

    // ---- prop step 1: in-register aggregate + conv + combine epilogue -> out ----
    gemm_fused<HF, 2><<<GB, 256, 0, stream>>>(
        nullptr, hbf2, fc, conv_b, out, nullptr,
        h0, deg_inv, dis, root_emb, nullptr, nullptr,
        row_start, csr_col, nullptr, nullptr, nullptr, 0, N);
}